// Round 9
// baseline (239.477 us; speedup 1.0000x reference)
//
#include <hip/hip_runtime.h>

#define N_STK 768
#define BATCH 2
#define WIN   32
#define FEAT  4
#define UNITS 32
#define INP   72      // 2U + K
#define LROW  76      // padded LDS row stride (dwords), 16B-aligned
#define NSLC  19      // 16B slices per padded row (slice 18 = pad, dummy load)
#define IPH   64      // xi rows per i-phase tile
#define JCR   24      // columns per tile
#define NPHI  12      // 768/64
#define NCR   32      // 768/24

__device__ __forceinline__ float lrelu(float v){ return v > 0.0f ? v : 0.01f*v; }
__device__ __forceinline__ float lanebcast(float v, int l){
    return __int_as_float(__builtin_amdgcn_readlane(__float_as_int(v), l));
}
__device__ __forceinline__ unsigned patof(const float* __restrict__ p){
    float4 a = *reinterpret_cast<const float4*>(p);
    float4 b = *reinterpret_cast<const float4*>(p + 4);
    unsigned m = 0;
    m |= (a.x != 0.0f) ? 1u   : 0u;
    m |= (a.y != 0.0f) ? 2u   : 0u;
    m |= (a.z != 0.0f) ? 4u   : 0u;
    m |= (a.w != 0.0f) ? 8u   : 0u;
    m |= (b.x != 0.0f) ? 16u  : 0u;
    m |= (b.y != 0.0f) ? 32u  : 0u;
    m |= (b.z != 0.0f) ? 64u  : 0u;
    m |= (b.w != 0.0f) ? 128u : 0u;
    return m;
}
__device__ __forceinline__ void async_cp16(const float* g, float* l){
    __builtin_amdgcn_global_load_lds(
        (const __attribute__((address_space(1))) unsigned int*)g,
        (__attribute__((address_space(3))) unsigned int*)l,
        16, 0, 0);
}

// ---------------------------------------------------------------------------
// K1: block j: LSTM (waves 0,1), pattern row + degree (waves 2,3), then
// invD / s0,s1 zero / counter zero / LUT slices (j<64) / xi0,xj0 rows.
__global__ __launch_bounds__(256) void k1_kernel(const float* __restrict__ rel,
        const float* __restrict__ x, const float* __restrict__ Wih,
        const float* __restrict__ Whh, const float* __restrict__ bih,
        const float* __restrict__ bhh, const float* __restrict__ hop_w1,
        const float* __restrict__ hop_b1,
        float* __restrict__ seq, float* __restrict__ invD,
        unsigned char* __restrict__ Pout,
        float* __restrict__ lutlo, float* __restrict__ luthi,
        float* __restrict__ xi0, float* __restrict__ xj0,
        float* __restrict__ s0, float* __restrict__ s1,
        int* __restrict__ cnt0, int* __restrict__ cnt1){
    int j = blockIdx.x, tid = threadIdx.x;
    int wv = tid >> 6, lane = tid & 63;
    __shared__ float hrow[2][UNITS];
    __shared__ int cw_sh[2];

    if (wv < 2){
        int b = wv;
        int r0 = lane, r1 = 64 + lane;
        bool low = (lane < 32);
        float4 wi0 = *reinterpret_cast<const float4*>(Wih + r0*FEAT);
        float4 wi1 = *reinterpret_cast<const float4*>(Wih + r1*FEAT);
        float bb0 = bih[r0] + bhh[r0];
        float bb1 = bih[r1] + bhh[r1];
        float4 W0[8], W1[8];
        #pragma unroll
        for (int q = 0; q < 8; q++){
            W0[q] = *reinterpret_cast<const float4*>(Whh + r0*UNITS + q*4);
            W1[q] = *reinterpret_cast<const float4*>(Whh + r1*UNITS + q*4);
        }
        float4 xv = make_float4(0.f, 0.f, 0.f, 0.f);
        if (low) xv = *reinterpret_cast<const float4*>(x + ((size_t)(b*WIN + lane)*N_STK + j)*FEAT);
        float hreg = 0.0f, c = 0.0f;
        #pragma unroll 1
        for (int t = 0; t < WIN; t++){
            float xb0 = lanebcast(xv.x, t), xb1 = lanebcast(xv.y, t);
            float xb2 = lanebcast(xv.z, t), xb3 = lanebcast(xv.w, t);
            float z0a = bb0 + wi0.x*xb0 + wi0.z*xb2;
            float z0b =       wi0.y*xb1 + wi0.w*xb3;
            float z1a = bb1 + wi1.x*xb0 + wi1.z*xb2;
            float z1b =       wi1.y*xb1 + wi1.w*xb3;
            #pragma unroll
            for (int q = 0; q < 8; q++){
                float h0 = lanebcast(hreg, 32 + q*4 + 0);
                float h1 = lanebcast(hreg, 32 + q*4 + 1);
                float h2 = lanebcast(hreg, 32 + q*4 + 2);
                float h3 = lanebcast(hreg, 32 + q*4 + 3);
                z0a += W0[q].x*h0; z0b += W0[q].y*h1;
                z0a += W0[q].z*h2; z0b += W0[q].w*h3;
                z1a += W1[q].x*h0; z1b += W1[q].y*h1;
                z1a += W1[q].z*h2; z1b += W1[q].w*h3;
            }
            float z0 = z0a + z0b, z1 = z1a + z1b;
            float e0 = __expf(-z0);
            float sg = 1.0f/(1.0f + e0);                 // sig(i) / sig(f)
            float sc = low ? -2.0f : -1.0f;
            float e1 = __expf(sc*z1);
            float rr = 1.0f/(1.0f + e1);
            float act = low ? (1.0f - e1)*rr : rr;       // tanh(g) / sig(o)
            float pa = sg*act;
            float po = __shfl_xor(pa, 32);
            c = sg*c + po;
            float e2 = __expf(-2.0f*c);
            float th = (1.0f - e2)/(1.0f + e2);
            hreg = act*th;
        }
        if (!low){
            hrow[b][lane - 32] = hreg;
            seq[((size_t)b*N_STK + j)*UNITS + (lane - 32)] = hreg;
        }
    } else {
        int half = wv - 2;
        int local = 0;
        #pragma unroll
        for (int k = 0; k < 6; k++){
            int col = half*384 + k*64 + lane;
            unsigned pt = patof(rel + ((size_t)j*N_STK + col)*8);
            Pout[(size_t)j*N_STK + col] = (unsigned char)pt;
            local += pt ? 1 : 0;
        }
        #pragma unroll
        for (int d = 32; d; d >>= 1) local += __shfl_xor(local, d);
        if (lane == 0) cw_sh[half] = local;
    }
    __syncthreads();
    if (tid == 0){
        invD[j] = 1.0f/(float)(cw_sh[0] + cw_sh[1]);
        s0[j] = 0.0f; s0[N_STK + j] = 0.0f;
        s1[j] = 0.0f; s1[N_STK + j] = 0.0f;
    }
    if (j < 64 && tid == 1){ cnt0[j] = 0; cnt1[j] = 0; }
    if (j < 64 && tid >= 144 && tid < 216){
        int pp = tid - 144;
        int m = j & 15, half = (j >> 4) & 1, k = j >> 5;
        const float* W = hop_w1 + (size_t)k*INP*INP;
        float acc = half ? 0.0f : hop_b1[k*INP + pp];
        int base = 2*UNITS + (half ? 4 : 0);
        #pragma unroll
        for (int q = 0; q < 4; q++)
            if ((m >> q) & 1) acc += W[(base + q)*INP + pp];
        (half ? luthi : lutlo)[(k*16 + m)*INP + pp] = acc;
    }
    if (tid < 2*INP){
        int b = tid/INP, pp = tid - b*INP;
        float si = 0.0f, sj = 0.0f;
        #pragma unroll
        for (int u = 0; u < UNITS; u++){
            float ev = hrow[b][u];
            si += ev * hop_w1[u*INP + pp];
            sj += ev * hop_w1[(UNITS + u)*INP + pp];
        }
        size_t o = ((size_t)b*N_STK + j)*INP + pp;
        xi0[o] = si; xj0[o] = sj;
    }
}

// ---------------------------------------------------------------------------
// HOP kernel: tile (cr: 24 cols, ip: 64 rows, b). Dense async staging ONCE;
// wave-0 shfl-scan enumerate (no atomics), split mhi==0 (3 LDS streams) vs
// mhi!=0 (4 streams); per-col LDS partials -> 24 global atomics; then the
// LAST block per (b,cr) (fence+counter) runs the epilogue for its 24 columns.
// MODE 0: eA = seq*s, xi1/xj1 rows.  MODE 1: FC head -> out.
template<int MODE>
__global__ __launch_bounds__(256) void hop_kernel(const float* __restrict__ xi,
        const float* __restrict__ xj,
        const float* __restrict__ lutlo_k, const float* __restrict__ luthi_k,
        const float* __restrict__ w2, const float* __restrict__ b2,
        const unsigned char* __restrict__ P, const float* __restrict__ invD,
        float* __restrict__ s_out, int* __restrict__ cnt,
        const float* __restrict__ seqg, float* __restrict__ eA,
        const float* __restrict__ W1next, float* __restrict__ xi_next,
        float* __restrict__ xj_next,
        const float* __restrict__ fw1, const float* __restrict__ fb1,
        const float* __restrict__ fw2, const float* __restrict__ fb2,
        float* __restrict__ outp){
    int cr = blockIdx.x, ip = blockIdx.y, b = blockIdx.z;
    int j0 = cr*JCR, i0 = ip*IPH, tid = threadIdx.x;
    __shared__ float xi_sh[IPH*LROW];        // 19456 B (also epilogue scratch)
    __shared__ float xj_sh[JCR*LROW];        //  7296 B
    __shared__ float lo_sh[16*LROW];         //  4864 B
    __shared__ float hi_sh[16*LROW];         //  4864 B
    __shared__ float invD_sh[IPH];
    __shared__ float acc_sh[JCR];
    __shared__ float sarr[JCR];
    __shared__ unsigned elist[IPH*JCR];      //  6144 B
    __shared__ int n0_sh, nt_sh, isLast;

    const float* xib = xi + ((size_t)b*N_STK + i0)*INP;
    const float* xjb = xj + ((size_t)b*N_STK + j0)*INP;
    if (tid >= 224 && tid < 224 + JCR) acc_sh[tid - 224] = 0.0f;

    // ---- dense async staging (wave-uniform base + lane*16 slot maps) ----
    for (int u = tid; u < IPH*NSLC; u += 256){
        int r = u/NSLC, sl = u - r*NSLC;
        int off = (sl < 18) ? sl*4 : 0;
        async_cp16(xib + (size_t)r*INP + off, &xi_sh[0] + (size_t)u*4);
    }
    for (int u = tid; u < JCR*NSLC; u += 256){
        int r = u/NSLC, sl = u - r*NSLC;
        int off = (sl < 18) ? sl*4 : 0;
        async_cp16(xjb + (size_t)r*INP + off, &xj_sh[0] + (size_t)u*4);
    }
    for (int u = tid; u < 16*NSLC; u += 256){
        int r = u/NSLC, sl = u - r*NSLC;
        int off = (sl < 18) ? sl*4 : 0;
        async_cp16(lutlo_k + r*INP + off, &lo_sh[0] + (size_t)u*4);
    }
    for (int u = tid; u < 16*NSLC; u += 256){
        int r = u/NSLC, sl = u - r*NSLC;
        int off = (sl < 18) ? sl*4 : 0;
        async_cp16(luthi_k + r*INP + off, &hi_sh[0] + (size_t)u*4);
    }
    if (tid < IPH/4) async_cp16(invD + i0 + tid*4, &invD_sh[0] + tid*4);

    // ---- wave-0 enumerate: two-region, shfl prefix scan, no atomics ----
    if (tid < 64){
        const unsigned* prow = reinterpret_cast<const unsigned*>(P + (size_t)(i0 + tid)*N_STK + j0);
        unsigned w[6];
        #pragma unroll
        for (int k = 0; k < 6; k++) w[k] = prow[k];
        int c0 = 0, c1 = 0;
        #pragma unroll
        for (int k = 0; k < 24; k++){
            unsigned pat = (w[k >> 2] >> ((k & 3)*8)) & 255u;
            c0 += (pat && pat < 16u) ? 1 : 0;
            c1 += (pat >= 16u) ? 1 : 0;
        }
        int s0v = c0, s1v = c1;
        #pragma unroll
        for (int off = 1; off < 64; off <<= 1){
            int a0 = __shfl_up(s0v, off), a1 = __shfl_up(s1v, off);
            if (tid >= off){ s0v += a0; s1v += a1; }
        }
        int N0 = __shfl(s0v, 63);
        int Nt = N0 + __shfl(s1v, 63);
        int p0 = s0v - c0, p1 = N0 + s1v - c1;
        #pragma unroll
        for (int k = 0; k < 24; k++){
            unsigned pat = (w[k >> 2] >> ((k & 3)*8)) & 255u;
            unsigned enc = ((unsigned)tid << 13) | ((unsigned)k << 8) | pat;
            if (pat && pat < 16u) elist[p0++] = enc;
            else if (pat >= 16u)  elist[p1++] = enc;
        }
        if (tid == 0){ n0_sh = N0; nt_sh = Nt; }
    }

    int hf = tid & 1;
    float4 w2r[9];
    #pragma unroll
    for (int q = 0; q < 9; q++) w2r[q] = *reinterpret_cast<const float4*>(w2 + hf*36 + q*4);
    float b2v = b2[0];
    __syncthreads();   // drains async staging + elist + acc zero

    int n0 = n0_sh, ntot = nt_sh;
    // region A: mhi==0 (hi LUT row is exactly zero) — 3 LDS streams
    for (int sl = tid >> 1; sl < n0; sl += 128){
        unsigned ent = elist[sl];
        int il = ent >> 13, jl = (ent >> 8) & 31, mlo = (int)(ent & 15u);
        const float* xr = &xi_sh[il*LROW + hf*36];
        const float* jr = &xj_sh[jl*LROW + hf*36];
        const float* lr = &lo_sh[mlo*LROW + hf*36];
        float dot = 0.0f;
        #pragma unroll
        for (int q = 0; q < 9; q++){
            float4 xv = *reinterpret_cast<const float4*>(xr + q*4);
            float4 jv = *reinterpret_cast<const float4*>(jr + q*4);
            float4 lv = *reinterpret_cast<const float4*>(lr + q*4);
            float4 w  = w2r[q];
            dot += lrelu(xv.x + jv.x + lv.x)*w.x;
            dot += lrelu(xv.y + jv.y + lv.y)*w.y;
            dot += lrelu(xv.z + jv.z + lv.z)*w.z;
            dot += lrelu(xv.w + jv.w + lv.w)*w.w;
        }
        dot += __shfl_xor(dot, 1);
        if (hf == 0) atomicAdd(&acc_sh[jl], lrelu(dot + b2v)*invD_sh[il]);
    }
    // region B: mhi!=0 — 4 LDS streams
    for (int sl = n0 + (tid >> 1); sl < ntot; sl += 128){
        unsigned ent = elist[sl];
        int il = ent >> 13, jl = (ent >> 8) & 31;
        int mlo = (int)(ent & 15u), mhi = (int)((ent >> 4) & 15u);
        const float* xr = &xi_sh[il*LROW + hf*36];
        const float* jr = &xj_sh[jl*LROW + hf*36];
        const float* lr = &lo_sh[mlo*LROW + hf*36];
        const float* hr = &hi_sh[mhi*LROW + hf*36];
        float dot = 0.0f;
        #pragma unroll
        for (int q = 0; q < 9; q++){
            float4 xv = *reinterpret_cast<const float4*>(xr + q*4);
            float4 jv = *reinterpret_cast<const float4*>(jr + q*4);
            float4 lv = *reinterpret_cast<const float4*>(lr + q*4);
            float4 hv = *reinterpret_cast<const float4*>(hr + q*4);
            float4 w  = w2r[q];
            dot += lrelu(xv.x + jv.x + lv.x + hv.x)*w.x;
            dot += lrelu(xv.y + jv.y + lv.y + hv.y)*w.y;
            dot += lrelu(xv.z + jv.z + lv.z + hv.z)*w.z;
            dot += lrelu(xv.w + jv.w + lv.w + hv.w)*w.w;
        }
        dot += __shfl_xor(dot, 1);
        if (hf == 0) atomicAdd(&acc_sh[jl], lrelu(dot + b2v)*invD_sh[il]);
    }
    __syncthreads();
    if (tid < JCR) atomicAdd(&s_out[b*N_STK + j0 + tid], acc_sh[tid]);

    // ---- fence + counter: last block for (b,cr) runs the epilogue ----
    __threadfence();
    __syncthreads();
    if (tid == 0){
        int old = atomicAdd(&cnt[b*NCR + cr], 1);
        isLast = (old == NPHI - 1) ? 1 : 0;
    }
    __syncthreads();
    if (!isLast) return;

    // coherent re-read of the 24 finished s values (RMW = device-scope)
    if (tid < JCR) sarr[tid] = atomicAdd(&s_out[b*N_STK + j0 + tid], 0.0f);
    __syncthreads();

    if (MODE == 0){
        float* es = xi_sh;   // scratch: 24*32 floats
        for (int idx = tid; idx < JCR*UNITS; idx += 256){
            int c = idx >> 5, u = idx & 31;
            size_t o = ((size_t)b*N_STK + j0 + c)*UNITS + u;
            float ev = seqg[o]*sarr[c];
            eA[o] = ev;
            es[idx] = ev;
        }
        __syncthreads();
        for (int idx = tid; idx < JCR*INP; idx += 256){
            int c = idx/INP, pp = idx - c*INP;
            float si = 0.0f, sj = 0.0f;
            #pragma unroll
            for (int u = 0; u < UNITS; u++){
                float ev = es[c*UNITS + u];
                si += ev * W1next[u*INP + pp];
                sj += ev * W1next[(UNITS + u)*INP + pp];
            }
            size_t o = ((size_t)b*N_STK + j0 + c)*INP + pp;
            xi_next[o] = si; xj_next[o] = sj;
        }
    } else {
        float* comb = xi_sh;             // 24*64
        float* parr = xi_sh + JCR*64;    // 24*64
        for (int idx = tid; idx < JCR*64; idx += 256){
            int c = idx >> 6, d = idx & 63;
            size_t o = ((size_t)b*N_STK + j0 + c)*UNITS;
            comb[idx] = (d < 32) ? seqg[o + d] : eA[o + d - 32]*sarr[c];
        }
        __syncthreads();
        for (int idx = tid; idx < JCR*64; idx += 256){
            int c = idx >> 6, u = idx & 63;
            float acc = fb1[u];
            #pragma unroll 8
            for (int d = 0; d < 64; d++) acc += comb[c*64 + d]*fw1[d*64 + u];
            parr[idx] = lrelu(acc)*fw2[u];
        }
        __syncthreads();
        if (tid < JCR){
            float s = 0.0f;
            #pragma unroll 8
            for (int u = 0; u < 64; u++) s += parr[tid*64 + u];
            outp[b*N_STK + j0 + tid] = lrelu(s + fb2[0]);
        }
    }
}

// ---------------------------------------------------------------------------
extern "C" void kernel_launch(void* const* d_in, const int* in_sizes, int n_in,
                              void* d_out, int out_size, void* d_ws, size_t ws_size,
                              hipStream_t stream){
    const float* input_data = (const float*)d_in[0];
    const float* rel        = (const float*)d_in[1];
    const float* lstm_Wih   = (const float*)d_in[2];
    const float* lstm_Whh   = (const float*)d_in[3];
    const float* lstm_bih   = (const float*)d_in[4];
    const float* lstm_bhh   = (const float*)d_in[5];
    const float* hop_w1     = (const float*)d_in[6];
    const float* hop_b1     = (const float*)d_in[7];
    const float* hop_w2     = (const float*)d_in[8];
    const float* hop_b2     = (const float*)d_in[9];
    const float* fn_w1      = (const float*)d_in[10];
    const float* fn_b1      = (const float*)d_in[11];
    const float* fn_w2      = (const float*)d_in[12];
    const float* fn_b2      = (const float*)d_in[13];
    float* out = (float*)d_out;

    float* ws    = (float*)d_ws;
    float* seq   = ws;                    // 49152
    float* eA    = seq   + 49152;         // 49152
    float* xi0   = eA    + 49152;         // 110592
    float* xj0   = xi0   + 110592;
    float* xi1   = xj0   + 110592;
    float* xj1   = xi1   + 110592;
    float* lutlo = xj1   + 110592;        // 2304
    float* luthi = lutlo + 2304;
    float* invD  = luthi + 2304;          // 768
    float* s0    = invD  + 768;           // 1536
    float* s1    = s0    + 1536;          // 1536
    int*   cnt0  = (int*)(s1 + 1536);     // 64
    int*   cnt1  = cnt0  + 64;            // 64
    unsigned char* P = (unsigned char*)(cnt1 + 64);  // 768*768 bytes

    k1_kernel<<<N_STK, 256, 0, stream>>>(rel, input_data, lstm_Wih, lstm_Whh,
            lstm_bih, lstm_bhh, hop_w1, hop_b1,
            seq, invD, P, lutlo, luthi, xi0, xj0, s0, s1, cnt0, cnt1);

    dim3 hgrid(NCR, NPHI, BATCH);
    hop_kernel<0><<<hgrid, 256, 0, stream>>>(xi0, xj0, lutlo, luthi,
            hop_w2, hop_b2, P, invD, s0, cnt0,
            seq, eA, hop_w1 + INP*INP, xi1, xj1,
            nullptr, nullptr, nullptr, nullptr, nullptr);

    hop_kernel<1><<<hgrid, 256, 0, stream>>>(xi1, xj1, lutlo + 16*INP, luthi + 16*INP,
            hop_w2 + INP, hop_b2 + 1, P, invD, s1, cnt1,
            seq, eA, nullptr, nullptr, nullptr,
            fn_w1, fn_b1, fn_w2, fn_b2, out);
}

// Round 10
// 147.458 us; speedup vs baseline: 1.6240x; 1.6240x over previous
//
#include <hip/hip_runtime.h>

#define N_STK 768
#define BATCH 2
#define WIN   32
#define FEAT  4
#define UNITS 32
#define INP   72      // 2U + K
#define LROW  76      // padded LDS row stride (dwords), 16B-aligned
#define NSLC  19      // 16B slices per padded row (slice 18 = pad, dummy load)
#define IPH   48      // xi rows per i-phase tile (36.7 KB LDS -> 4 blocks/CU)
#define JCR   24      // columns per tile
#define NPHI  16      // 768/48
#define NCR   32      // 768/24

__device__ __forceinline__ float lrelu(float v){ return v > 0.0f ? v : 0.01f*v; }
__device__ __forceinline__ float lanebcast(float v, int l){
    return __int_as_float(__builtin_amdgcn_readlane(__float_as_int(v), l));
}
__device__ __forceinline__ unsigned patof(const float* __restrict__ p){
    float4 a = *reinterpret_cast<const float4*>(p);
    float4 b = *reinterpret_cast<const float4*>(p + 4);
    unsigned m = 0;
    m |= (a.x != 0.0f) ? 1u   : 0u;
    m |= (a.y != 0.0f) ? 2u   : 0u;
    m |= (a.z != 0.0f) ? 4u   : 0u;
    m |= (a.w != 0.0f) ? 8u   : 0u;
    m |= (b.x != 0.0f) ? 16u  : 0u;
    m |= (b.y != 0.0f) ? 32u  : 0u;
    m |= (b.z != 0.0f) ? 64u  : 0u;
    m |= (b.w != 0.0f) ? 128u : 0u;
    return m;
}
__device__ __forceinline__ void async_cp16(const float* g, float* l){
    __builtin_amdgcn_global_load_lds(
        (const __attribute__((address_space(1))) unsigned int*)g,
        (__attribute__((address_space(3))) unsigned int*)l,
        16, 0, 0);
}

// ---------------------------------------------------------------------------
// K1: block j: LSTM (waves 0,1), pattern row + degree (waves 2,3), then
// invD / s0 zero / LUT slices (j<64) / xi0,xj0 rows.
__global__ __launch_bounds__(256) void k1_kernel(const float* __restrict__ rel,
        const float* __restrict__ x, const float* __restrict__ Wih,
        const float* __restrict__ Whh, const float* __restrict__ bih,
        const float* __restrict__ bhh, const float* __restrict__ hop_w1,
        const float* __restrict__ hop_b1,
        float* __restrict__ seq, float* __restrict__ invD,
        unsigned char* __restrict__ Pout,
        float* __restrict__ lutlo, float* __restrict__ luthi,
        float* __restrict__ xi0, float* __restrict__ xj0,
        float* __restrict__ s0){
    int j = blockIdx.x, tid = threadIdx.x;
    int wv = tid >> 6, lane = tid & 63;
    __shared__ float hrow[2][UNITS];
    __shared__ int cw_sh[2];

    if (wv < 2){
        int b = wv;
        int r0 = lane, r1 = 64 + lane;
        bool low = (lane < 32);
        float4 wi0 = *reinterpret_cast<const float4*>(Wih + r0*FEAT);
        float4 wi1 = *reinterpret_cast<const float4*>(Wih + r1*FEAT);
        float bb0 = bih[r0] + bhh[r0];
        float bb1 = bih[r1] + bhh[r1];
        float4 W0[8], W1[8];
        #pragma unroll
        for (int q = 0; q < 8; q++){
            W0[q] = *reinterpret_cast<const float4*>(Whh + r0*UNITS + q*4);
            W1[q] = *reinterpret_cast<const float4*>(Whh + r1*UNITS + q*4);
        }
        float4 xv = make_float4(0.f, 0.f, 0.f, 0.f);
        if (low) xv = *reinterpret_cast<const float4*>(x + ((size_t)(b*WIN + lane)*N_STK + j)*FEAT);
        float hreg = 0.0f, c = 0.0f;
        #pragma unroll 1
        for (int t = 0; t < WIN; t++){
            float xb0 = lanebcast(xv.x, t), xb1 = lanebcast(xv.y, t);
            float xb2 = lanebcast(xv.z, t), xb3 = lanebcast(xv.w, t);
            float z0a = bb0 + wi0.x*xb0 + wi0.z*xb2;
            float z0b =       wi0.y*xb1 + wi0.w*xb3;
            float z1a = bb1 + wi1.x*xb0 + wi1.z*xb2;
            float z1b =       wi1.y*xb1 + wi1.w*xb3;
            #pragma unroll
            for (int q = 0; q < 8; q++){
                float h0 = lanebcast(hreg, 32 + q*4 + 0);
                float h1 = lanebcast(hreg, 32 + q*4 + 1);
                float h2 = lanebcast(hreg, 32 + q*4 + 2);
                float h3 = lanebcast(hreg, 32 + q*4 + 3);
                z0a += W0[q].x*h0; z0b += W0[q].y*h1;
                z0a += W0[q].z*h2; z0b += W0[q].w*h3;
                z1a += W1[q].x*h0; z1b += W1[q].y*h1;
                z1a += W1[q].z*h2; z1b += W1[q].w*h3;
            }
            float z0 = z0a + z0b, z1 = z1a + z1b;
            float e0 = __expf(-z0);
            float sg = 1.0f/(1.0f + e0);                 // sig(i) / sig(f)
            float sc = low ? -2.0f : -1.0f;
            float e1 = __expf(sc*z1);
            float rr = 1.0f/(1.0f + e1);
            float act = low ? (1.0f - e1)*rr : rr;       // tanh(g) / sig(o)
            float pa = sg*act;
            float po = __shfl_xor(pa, 32);
            c = sg*c + po;
            float e2 = __expf(-2.0f*c);
            float th = (1.0f - e2)/(1.0f + e2);
            hreg = act*th;
        }
        if (!low){
            hrow[b][lane - 32] = hreg;
            seq[((size_t)b*N_STK + j)*UNITS + (lane - 32)] = hreg;
        }
    } else {
        int half = wv - 2;
        int local = 0;
        #pragma unroll
        for (int k = 0; k < 6; k++){
            int col = half*384 + k*64 + lane;
            unsigned pt = patof(rel + ((size_t)j*N_STK + col)*8);
            Pout[(size_t)j*N_STK + col] = (unsigned char)pt;
            local += pt ? 1 : 0;
        }
        #pragma unroll
        for (int d = 32; d; d >>= 1) local += __shfl_xor(local, d);
        if (lane == 0) cw_sh[half] = local;
    }
    __syncthreads();
    if (tid == 0){
        invD[j] = 1.0f/(float)(cw_sh[0] + cw_sh[1]);
        s0[j] = 0.0f; s0[N_STK + j] = 0.0f;
    }
    if (j < 64 && tid >= 144 && tid < 216){
        int pp = tid - 144;
        int m = j & 15, half = (j >> 4) & 1, k = j >> 5;
        const float* W = hop_w1 + (size_t)k*INP*INP;
        float acc = half ? 0.0f : hop_b1[k*INP + pp];
        int base = 2*UNITS + (half ? 4 : 0);
        #pragma unroll
        for (int q = 0; q < 4; q++)
            if ((m >> q) & 1) acc += W[(base + q)*INP + pp];
        (half ? luthi : lutlo)[(k*16 + m)*INP + pp] = acc;
    }
    if (tid < 2*INP){
        int b = tid/INP, pp = tid - b*INP;
        float si = 0.0f, sj = 0.0f;
        #pragma unroll
        for (int u = 0; u < UNITS; u++){
            float ev = hrow[b][u];
            si += ev * hop_w1[u*INP + pp];
            sj += ev * hop_w1[(UNITS + u)*INP + pp];
        }
        size_t o = ((size_t)b*N_STK + j)*INP + pp;
        xi0[o] = si; xj0[o] = sj;
    }
}

// ---------------------------------------------------------------------------
// HOP kernel: tile (cr: 24 cols, ip: 48 rows, b). Dense async staging ONCE;
// wave-0 shfl-scan enumerate (no atomics), two-region split: mhi==0 entries
// (81.5%, hi LUT row exactly zero -> 3 LDS streams) then mhi!=0 (4 streams).
// Per-col LDS partials -> 24 global atomics. No fences, no epilogue.
__global__ __launch_bounds__(256) void hop_kernel(const float* __restrict__ xi,
        const float* __restrict__ xj,
        const float* __restrict__ lutlo_k, const float* __restrict__ luthi_k,
        const float* __restrict__ w2, const float* __restrict__ b2,
        const unsigned char* __restrict__ P, const float* __restrict__ invD,
        float* __restrict__ s_out){
    int cr = blockIdx.x, ip = blockIdx.y, b = blockIdx.z;
    int j0 = cr*JCR, i0 = ip*IPH, tid = threadIdx.x;
    __shared__ float xi_sh[IPH*LROW];        // 14592 B
    __shared__ float xj_sh[JCR*LROW];        //  7296 B
    __shared__ float lo_sh[16*LROW];         //  4864 B
    __shared__ float hi_sh[16*LROW];         //  4864 B
    __shared__ float invD_sh[IPH];
    __shared__ float acc_sh[JCR];
    __shared__ unsigned elist[IPH*JCR];      //  4608 B
    __shared__ int n0_sh, nt_sh;

    const float* xib = xi + ((size_t)b*N_STK + i0)*INP;
    const float* xjb = xj + ((size_t)b*N_STK + j0)*INP;
    if (tid >= 224 && tid < 224 + JCR) acc_sh[tid - 224] = 0.0f;

    // ---- dense async staging (wave-uniform base + lane*16 slot maps) ----
    for (int u = tid; u < IPH*NSLC; u += 256){
        int r = u/NSLC, sl = u - r*NSLC;
        int off = (sl < 18) ? sl*4 : 0;
        async_cp16(xib + (size_t)r*INP + off, &xi_sh[0] + (size_t)u*4);
    }
    for (int u = tid; u < JCR*NSLC; u += 256){
        int r = u/NSLC, sl = u - r*NSLC;
        int off = (sl < 18) ? sl*4 : 0;
        async_cp16(xjb + (size_t)r*INP + off, &xj_sh[0] + (size_t)u*4);
    }
    for (int u = tid; u < 16*NSLC; u += 256){
        int r = u/NSLC, sl = u - r*NSLC;
        int off = (sl < 18) ? sl*4 : 0;
        async_cp16(lutlo_k + r*INP + off, &lo_sh[0] + (size_t)u*4);
    }
    for (int u = tid; u < 16*NSLC; u += 256){
        int r = u/NSLC, sl = u - r*NSLC;
        int off = (sl < 18) ? sl*4 : 0;
        async_cp16(luthi_k + r*INP + off, &hi_sh[0] + (size_t)u*4);
    }
    if (tid < IPH/4) async_cp16(invD + i0 + tid*4, &invD_sh[0] + tid*4);

    // ---- wave-0 enumerate: two-region, shfl prefix scan, no atomics ----
    if (tid < 64){
        unsigned w[6] = {0,0,0,0,0,0};
        int c0 = 0, c1 = 0;
        if (tid < IPH){
            const unsigned* prow = reinterpret_cast<const unsigned*>(P + (size_t)(i0 + tid)*N_STK + j0);
            #pragma unroll
            for (int k = 0; k < 6; k++) w[k] = prow[k];
            #pragma unroll
            for (int k = 0; k < 24; k++){
                unsigned pat = (w[k >> 2] >> ((k & 3)*8)) & 255u;
                c0 += (pat && pat < 16u) ? 1 : 0;
                c1 += (pat >= 16u) ? 1 : 0;
            }
        }
        int s0v = c0, s1v = c1;
        #pragma unroll
        for (int off = 1; off < 64; off <<= 1){
            int a0 = __shfl_up(s0v, off), a1 = __shfl_up(s1v, off);
            if (tid >= off){ s0v += a0; s1v += a1; }
        }
        int N0 = __shfl(s0v, 63);
        int Nt = N0 + __shfl(s1v, 63);
        if (tid < IPH){
            int p0 = s0v - c0, p1 = N0 + s1v - c1;
            #pragma unroll
            for (int k = 0; k < 24; k++){
                unsigned pat = (w[k >> 2] >> ((k & 3)*8)) & 255u;
                unsigned enc = ((unsigned)tid << 13) | ((unsigned)k << 8) | pat;
                if (pat && pat < 16u) elist[p0++] = enc;
                else if (pat >= 16u)  elist[p1++] = enc;
            }
        }
        if (tid == 0){ n0_sh = N0; nt_sh = Nt; }
    }

    int hf = tid & 1;
    float4 w2r[9];
    #pragma unroll
    for (int q = 0; q < 9; q++) w2r[q] = *reinterpret_cast<const float4*>(w2 + hf*36 + q*4);
    float b2v = b2[0];
    __syncthreads();   // drains async staging + elist + acc zero

    int n0 = n0_sh, ntot = nt_sh;
    // region A: mhi==0 (hi LUT row is exactly zero) — 3 LDS streams
    for (int sl = tid >> 1; sl < n0; sl += 128){
        unsigned ent = elist[sl];
        int il = ent >> 13, jl = (ent >> 8) & 31, mlo = (int)(ent & 15u);
        const float* xr = &xi_sh[il*LROW + hf*36];
        const float* jr = &xj_sh[jl*LROW + hf*36];
        const float* lr = &lo_sh[mlo*LROW + hf*36];
        float dot = 0.0f;
        #pragma unroll
        for (int q = 0; q < 9; q++){
            float4 xv = *reinterpret_cast<const float4*>(xr + q*4);
            float4 jv = *reinterpret_cast<const float4*>(jr + q*4);
            float4 lv = *reinterpret_cast<const float4*>(lr + q*4);
            float4 w  = w2r[q];
            dot += lrelu(xv.x + jv.x + lv.x)*w.x;
            dot += lrelu(xv.y + jv.y + lv.y)*w.y;
            dot += lrelu(xv.z + jv.z + lv.z)*w.z;
            dot += lrelu(xv.w + jv.w + lv.w)*w.w;
        }
        dot += __shfl_xor(dot, 1);
        if (hf == 0) atomicAdd(&acc_sh[jl], lrelu(dot + b2v)*invD_sh[il]);
    }
    // region B: mhi!=0 — 4 LDS streams
    for (int sl = n0 + (tid >> 1); sl < ntot; sl += 128){
        unsigned ent = elist[sl];
        int il = ent >> 13, jl = (ent >> 8) & 31;
        int mlo = (int)(ent & 15u), mhi = (int)((ent >> 4) & 15u);
        const float* xr = &xi_sh[il*LROW + hf*36];
        const float* jr = &xj_sh[jl*LROW + hf*36];
        const float* lr = &lo_sh[mlo*LROW + hf*36];
        const float* hr = &hi_sh[mhi*LROW + hf*36];
        float dot = 0.0f;
        #pragma unroll
        for (int q = 0; q < 9; q++){
            float4 xv = *reinterpret_cast<const float4*>(xr + q*4);
            float4 jv = *reinterpret_cast<const float4*>(jr + q*4);
            float4 lv = *reinterpret_cast<const float4*>(lr + q*4);
            float4 hv = *reinterpret_cast<const float4*>(hr + q*4);
            float4 w  = w2r[q];
            dot += lrelu(xv.x + jv.x + lv.x + hv.x)*w.x;
            dot += lrelu(xv.y + jv.y + lv.y + hv.y)*w.y;
            dot += lrelu(xv.z + jv.z + lv.z + hv.z)*w.z;
            dot += lrelu(xv.w + jv.w + lv.w + hv.w)*w.w;
        }
        dot += __shfl_xor(dot, 1);
        if (hf == 0) atomicAdd(&acc_sh[jl], lrelu(dot + b2v)*invD_sh[il]);
    }
    __syncthreads();
    if (tid < JCR) atomicAdd(&s_out[b*N_STK + j0 + tid], acc_sh[tid]);
}

// ---------------------------------------------------------------------------
// Epilogues. MODE 0 (after hop0): eA = seq*s0, xi1/xj1 rows, zero s1.
// MODE 1 (after hop1): FC head on [seq, eA*s1] -> out.
template<int MODE>
__global__ __launch_bounds__(192) void ep_kernel(const float* __restrict__ sview,
        const float* __restrict__ ein, const float* __restrict__ seqg,
        float* __restrict__ eout,
        const float* __restrict__ W1next, float* __restrict__ xi_next,
        float* __restrict__ xj_next, float* __restrict__ s_next,
        const float* __restrict__ fw1, const float* __restrict__ fb1,
        const float* __restrict__ fw2, const float* __restrict__ fb2,
        float* __restrict__ outp){
    int j = blockIdx.x, tid = threadIdx.x;
    __shared__ float e_sh[2][64];
    if (tid < 64){
        int b = tid >> 5, u = tid & 31;
        size_t o = ((size_t)b*N_STK + j)*UNITS + u;
        float ev = ein[o]*sview[b*N_STK + j];
        if (MODE == 0){ e_sh[b][u] = ev; eout[o] = ev; }
        else          { e_sh[b][32 + u] = ev; e_sh[b][u] = seqg[o]; }
    }
    if (MODE == 0 && tid >= 160 && tid < 162) s_next[(tid - 160)*N_STK + j] = 0.0f;
    __syncthreads();
    if (MODE == 0){
        if (tid < 2*INP){
            int b = tid/INP, pp = tid - b*INP;
            float si = 0.0f, sj = 0.0f;
            #pragma unroll
            for (int u = 0; u < UNITS; u++){
                float ev = e_sh[b][u];
                si += ev * W1next[u*INP + pp];
                sj += ev * W1next[(UNITS + u)*INP + pp];
            }
            size_t o = ((size_t)b*N_STK + j)*INP + pp;
            xi_next[o] = si; xj_next[o] = sj;
        }
    } else {
        if (tid < 128){
            int b = tid >> 6, u = tid & 63;
            float acc = fb1[u];
            #pragma unroll 8
            for (int d = 0; d < 64; d++) acc += e_sh[b][d]*fw1[d*64 + u];
            float prod = lrelu(acc)*fw2[u];
            prod += __shfl_xor(prod, 32);
            prod += __shfl_xor(prod, 16);
            prod += __shfl_xor(prod, 8);
            prod += __shfl_xor(prod, 4);
            prod += __shfl_xor(prod, 2);
            prod += __shfl_xor(prod, 1);
            if (u == 0) outp[b*N_STK + j] = lrelu(prod + fb2[0]);
        }
    }
}

// ---------------------------------------------------------------------------
extern "C" void kernel_launch(void* const* d_in, const int* in_sizes, int n_in,
                              void* d_out, int out_size, void* d_ws, size_t ws_size,
                              hipStream_t stream){
    const float* input_data = (const float*)d_in[0];
    const float* rel        = (const float*)d_in[1];
    const float* lstm_Wih   = (const float*)d_in[2];
    const float* lstm_Whh   = (const float*)d_in[3];
    const float* lstm_bih   = (const float*)d_in[4];
    const float* lstm_bhh   = (const float*)d_in[5];
    const float* hop_w1     = (const float*)d_in[6];
    const float* hop_b1     = (const float*)d_in[7];
    const float* hop_w2     = (const float*)d_in[8];
    const float* hop_b2     = (const float*)d_in[9];
    const float* fn_w1      = (const float*)d_in[10];
    const float* fn_b1      = (const float*)d_in[11];
    const float* fn_w2      = (const float*)d_in[12];
    const float* fn_b2      = (const float*)d_in[13];
    float* out = (float*)d_out;

    float* ws    = (float*)d_ws;
    float* seq   = ws;                    // 49152
    float* eA    = seq   + 49152;         // 49152
    float* xi0   = eA    + 49152;         // 110592
    float* xj0   = xi0   + 110592;
    float* xi1   = xj0   + 110592;
    float* xj1   = xi1   + 110592;
    float* lutlo = xj1   + 110592;        // 2304
    float* luthi = lutlo + 2304;
    float* invD  = luthi + 2304;          // 768
    float* s0    = invD  + 768;           // 1536
    float* s1    = s0    + 1536;          // 1536
    unsigned char* P = (unsigned char*)(s1 + 1536);  // 768*768 bytes

    k1_kernel<<<N_STK, 256, 0, stream>>>(rel, input_data, lstm_Wih, lstm_Whh,
            lstm_bih, lstm_bhh, hop_w1, hop_b1,
            seq, invD, P, lutlo, luthi, xi0, xj0, s0);

    dim3 hgrid(NCR, NPHI, BATCH);
    hop_kernel<<<hgrid, 256, 0, stream>>>(xi0, xj0, lutlo, luthi,
            hop_w2, hop_b2, P, invD, s0);

    ep_kernel<0><<<N_STK, 192, 0, stream>>>(s0, seq, nullptr, eA,
            hop_w1 + INP*INP, xi1, xj1, s1,
            nullptr, nullptr, nullptr, nullptr, nullptr);

    hop_kernel<<<hgrid, 256, 0, stream>>>(xi1, xj1, lutlo + 16*INP, luthi + 16*INP,
            hop_w2 + INP, hop_b2 + 1, P, invD, s1);

    ep_kernel<1><<<N_STK, 192, 0, stream>>>(s1, eA, seq, nullptr,
            nullptr, nullptr, nullptr, nullptr,
            fn_w1, fn_b1, fn_w2, fn_b2, out);
}